// Round 8
// baseline (309.942 us; speedup 1.0000x reference)
//
#include <hip/hip_runtime.h>
#include <math.h>

#define HID 256
#define SEQ 512

typedef float v4f __attribute__((ext_vector_type(4)));
typedef float v2f __attribute__((ext_vector_type(2)));

// ---------------------------------------------------------------------------
// Phase 1: inp[t][i] = b[i] + sum_j emb[idx[t]][j] * W[i][HID + j]
// One block per timestep t (512 blocks), 256 threads (one per output i).
// ---------------------------------------------------------------------------
__global__ __launch_bounds__(256) void qrnn_phase1(
    const int* __restrict__ idx, const float* __restrict__ emb,
    const float* __restrict__ W, const float* __restrict__ b,
    float* __restrict__ inp)
{
    const int t = blockIdx.x;
    const int i = threadIdx.x;
    __shared__ float xs[HID];
    const size_t row = (size_t)idx[t];
    xs[i] = emb[row * HID + i];
    __syncthreads();

    const float* wr = W + (size_t)i * (2 * HID) + HID;  // Wx row i
    float acc = b[i];
#pragma unroll
    for (int k = 0; k < HID / 4; ++k) {
        const float4 w4 = *reinterpret_cast<const float4*>(wr + k * 4);
        const float4 x4 = *reinterpret_cast<const float4*>(&xs[k * 4]);
        acc = fmaf(w4.x, x4.x, acc);
        acc = fmaf(w4.y, x4.y, acc);
        acc = fmaf(w4.z, x4.z, acc);
        acc = fmaf(w4.w, x4.w, acc);
    }
    inp[t * HID + i] = acc;
}

// DPP move from another lane (VALU pipe, no LDS).
// Direction convention (verified in round 5, which passed): row_ror:n ->
// lane i reads lane (i-n)&15.
// CTRLs: 0xB1 quad_perm(1,0,3,2)=xor1 (self-inverse);
//        0x4E quad_perm(2,3,0,1)=xor2 (self-inverse);
//        0x128 ROW_ROR:8 = lane^8 (self-inverse);
//        0x124 ROW_ROR:4  -> src (i-4)&15 (partner for lanes with r&4==1);
//        0x12C ROW_ROR:12 -> src (i+4)&15 (partner for lanes with r&4==0).
template <int CTRL>
__device__ __forceinline__ float dpp_mov(float v)
{
    return __int_as_float(
        __builtin_amdgcn_update_dpp(0, __float_as_int(v), CTRL, 0xF, 0xF, true));
}

// Packed f32 FMA where the WEIGHT is an in-out operand. The asm pretend-
// defines w every use, so the next iteration's use consumes THIS asm's
// output — an asm result is not rematerializable, so regalloc cannot
// re-derive the weight from its originating load (rounds 2-6 failure mode:
// weights re-fetched from L1/L2 every step, ~256 KB/step = ~1250 cy/step
// bandwidth wall; VGPR_Count ~90 proved nothing stayed resident).
// w is not actually modified: semantics preserved.
__device__ __forceinline__ void pk_fma_w(v2f& acc, v2f& w, v2f h)
{
    asm("v_pk_fma_f32 %0, %1, %2, %0" : "+v"(acc), "+v"(w) : "v"(h));
}

// ---------------------------------------------------------------------------
// Phase 2: sequential scan, single block of 512 threads (8 waves, 2/SIMD).
// Round-5 verified layout: 16-lane groups (one DPP row), r = tid&15,
// g = tid>>4 (32 groups). Group g owns rows [8g,8g+8); lane r owns cols
// [16r,16r+16). LDS read traffic 32 KB/step.
// Weight tile: 8 rows x 8 col-pairs = 64 v2f = 128 floats, held in VGPRs
// by the in-out asm trick (see pk_fma_w). Pressure ~185 regs < 256 budget
// at 2 waves/EU (waves_per_eu(2,2), and a 512-thread block forces >=2 anyway).
// h double-buffered in LDS, word-swizzle sw(w) = w ^ (((w>>5)&7)<<2).
// Reduction: DPP reduce-scatter over lane bits {0,1,3}, then butterfly over
// bit2 (code identical to round 5, which passed at absmax 1.5e-5).
// ---------------------------------------------------------------------------
__global__ void __launch_bounds__(512)
__attribute__((amdgpu_waves_per_eu(2, 2)))
qrnn_phase2(const float* __restrict__ W, const float* __restrict__ inp,
            float* __restrict__ out)
{
    const int tid = threadIdx.x;
    const int r = tid & 15;
    const int g = tid >> 4;                 // [0, 32)
    const bool b0 = (r & 1) != 0;
    const bool b1 = (r & 2) != 0;
    const bool b2 = (r & 4) != 0;
    const bool b3 = (r & 8) != 0;
    const int m_r = (r & 3) | ((r >> 1) & 4);   // this lane's output row-in-group
    const int i_out = 8 * g + m_r;

    __shared__ float hbuf[2][HID];
    if (tid < HID) hbuf[0][tid] = 0.0f;

    // Weight tile: wp[m][k] = W[(8g+m)][16r + 2k, 16r + 2k + 1]
    v2f wp[8][8];
#pragma unroll
    for (int m = 0; m < 8; ++m) {
        const float* wrow = W + (size_t)(8 * g + m) * (2 * HID) + r * 16;
#pragma unroll
        for (int k = 0; k < 8; ++k)
            wp[m][k] = *reinterpret_cast<const v2f*>(wrow + 2 * k);
    }

    // Loop-invariant swizzled word offsets (round-5 pattern)
    int rdoff[4];
#pragma unroll
    for (int k = 0; k < 4; ++k) {
        const int w = 16 * r + 4 * k;
        rdoff[k] = w ^ (((w >> 5) & 7) << 2);
    }
    const int wroff = i_out ^ (((i_out >> 5) & 7) << 2);

    float ip = inp[i_out];  // inp[0][i_out]
    float h = 0.0f;
    __syncthreads();

    auto step = [&](const float* __restrict__ src, float* __restrict__ dst,
                    int tnext) {
        // This lane's 16 h values: 4 swizzled float4 reads
        v4f h4[4];
#pragma unroll
        for (int k = 0; k < 4; ++k)
            h4[k] = *reinterpret_cast<const v4f*>(src + rdoff[k]);

        // Col-pair vectors matching wp's columns (subregister extraction)
        v2f hp[8];
#pragma unroll
        for (int k = 0; k < 4; ++k) {
            hp[2 * k]     = (v2f){ h4[k].x, h4[k].y };
            hp[2 * k + 1] = (v2f){ h4[k].z, h4[k].w };
        }

        // Prefetch next step's inp (branchless; hidden under FMAs)
        float ip_next = inp[(tnext & (SEQ - 1)) * HID + i_out];

        // 8 partial dots, 8 packed FMAs each (64 pk_fma = 128 MACs),
        // weights locked into VGPRs by the in-out asm chain.
        v2f acc2[8];
#pragma unroll
        for (int m = 0; m < 8; ++m) {
            acc2[m] = (v2f){ 0.0f, 0.0f };
#pragma unroll
            for (int k = 0; k < 8; ++k)
                pk_fma_w(acc2[m], wp[m][k], hp[k]);
        }
        float acc[8];
#pragma unroll
        for (int m = 0; m < 8; ++m)
            acc[m] = acc2[m].x + acc2[m].y;

        // --- DPP reduce-scatter across the 16-lane group (round-5 code) ---
        // Stage 1: lane bit0 <-> row bit0 (8 -> 4).
        float q[4];
#pragma unroll
        for (int j = 0; j < 4; ++j) {
            float give = b0 ? acc[2 * j] : acc[2 * j + 1];
            float keep = b0 ? acc[2 * j + 1] : acc[2 * j];
            q[j] = keep + dpp_mov<0xB1>(give);
        }
        // Stage 2: lane bit1 <-> row bit1 (4 -> 2).
        float s2[2];
#pragma unroll
        for (int k2 = 0; k2 < 2; ++k2) {
            float give = b1 ? q[2 * k2] : q[2 * k2 + 1];
            float keep = b1 ? q[2 * k2 + 1] : q[2 * k2];
            s2[k2] = keep + dpp_mov<0x4E>(give);
        }
        // Stage 3: lane bit3 <-> row bit2 (2 -> 1). lane^8 = ROW_ROR:8.
        float give3 = b3 ? s2[0] : s2[1];
        float keep3 = b3 ? s2[1] : s2[0];
        float ssum = keep3 + dpp_mov<0x128>(give3);
        // Stage 4: butterfly over lane bit2; partner r^4.
        float a4  = dpp_mov<0x124>(ssum);   // src (i-4)&15
        float a12 = dpp_mov<0x12C>(ssum);   // src (i+4)&15
        float total = ssum + (b2 ? a4 : a12);

        float d = total + ip;
        // tanh(d) = 1 - 2/(exp(2d)+1)
        float e = __expf(2.0f * d);
        h = 1.0f - 2.0f / (e + 1.0f);

        // Writer lanes (b2==0) store h_new[i_out] (swizzled word).
        if (!b2) dst[wroff] = h;

        ip = ip_next;
        __syncthreads();
    };

#pragma unroll 1
    for (int t = 0; t < SEQ; t += 2) {
        step(&hbuf[0][0], &hbuf[1][0], t + 1);
        step(&hbuf[1][0], &hbuf[0][0], t + 2);
    }

    if (!b2) out[i_out] = h;
}

extern "C" void kernel_launch(void* const* d_in, const int* in_sizes, int n_in,
                              void* d_out, int out_size, void* d_ws, size_t ws_size,
                              hipStream_t stream)
{
    const int*   idx = (const int*)d_in[0];
    const float* emb = (const float*)d_in[1];
    const float* W   = (const float*)d_in[2];
    const float* b   = (const float*)d_in[3];
    float* out = (float*)d_out;
    float* inp = (float*)d_ws;  // SEQ*HID*4 = 512 KB scratch

    qrnn_phase1<<<SEQ, HID, 0, stream>>>(idx, emb, W, b, inp);
    qrnn_phase2<<<1, 512, 0, stream>>>(W, inp, out);
}

// Round 9
// 287.755 us; speedup vs baseline: 1.0771x; 1.0771x over previous
//
#include <hip/hip_runtime.h>
#include <math.h>

#define HID 256
#define SEQ 512

typedef _Float16 v2h __attribute__((ext_vector_type(2)));
typedef float v4f __attribute__((ext_vector_type(4)));

// ---------------------------------------------------------------------------
// Phase 1: inp[t][i] = b[i] + sum_j emb[idx[t]][j] * W[i][HID + j]   (all f32)
// ---------------------------------------------------------------------------
__global__ __launch_bounds__(256) void qrnn_phase1(
    const int* __restrict__ idx, const float* __restrict__ emb,
    const float* __restrict__ W, const float* __restrict__ b,
    float* __restrict__ inp)
{
    const int t = blockIdx.x;
    const int i = threadIdx.x;
    __shared__ float xs[HID];
    const size_t row = (size_t)idx[t];
    xs[i] = emb[row * HID + i];
    __syncthreads();

    const float* wr = W + (size_t)i * (2 * HID) + HID;  // Wx row i
    float acc = b[i];
#pragma unroll
    for (int k = 0; k < HID / 4; ++k) {
        const float4 w4 = *reinterpret_cast<const float4*>(wr + k * 4);
        const float4 x4 = *reinterpret_cast<const float4*>(&xs[k * 4]);
        acc = fmaf(w4.x, x4.x, acc);
        acc = fmaf(w4.y, x4.y, acc);
        acc = fmaf(w4.z, x4.z, acc);
        acc = fmaf(w4.w, x4.w, acc);
    }
    inp[t * HID + i] = acc;
}

// DPP move from another lane (VALU pipe). Direction verified in rounds 5/8:
// row_ror:n -> lane i reads lane (i-n)&15.
// 0xB1 xor1; 0x4E xor2; 0x128 ROW_ROR:8 = lane^8; 0x124 ROR:4 src (i-4)&15;
// 0x12C ROR:12 src (i+4)&15.
template <int CTRL>
__device__ __forceinline__ float dpp_mov(float v)
{
    return __int_as_float(
        __builtin_amdgcn_update_dpp(0, __float_as_int(v), CTRL, 0xF, 0xF, true));
}

// One-time pin: makes the converted f16 weights asm-defined (not remat-able
// from the W loads + converts). With only 64 regs needed, pressure (~95)
// sits at the allocator's observed ~88-110 arch grant -> VGPR-resident,
// no AGPR copies (rounds 3-8 failure mode needed 128 regs and lost).
#define PIN8(a) asm volatile("" : "+v"(a[0]), "+v"(a[1]), "+v"(a[2]), \
                                  "+v"(a[3]), "+v"(a[4]), "+v"(a[5]), \
                                  "+v"(a[6]), "+v"(a[7]))

// ---------------------------------------------------------------------------
// Phase 2: sequential scan, 512 threads (8 waves, 2/SIMD), f16 weights/h.
// 16-lane groups: r = tid&15, g = tid>>4 (32 groups). Group g owns rows
// [8g,8g+8); lane r owns cols [16r,16r+16) as 8 half2 = 64 VGPRs.
// MACs via v_dot2_f32_f16 (2 MACs/instr, f32 accumulate).
// Precision: f16 RTN err 2^-12; per-step dot rms ~1.2e-4; recurrence gain
// sigma*sqrt(2N)*(1-h^2) ~ 0.5 < 1 -> steady-state ~2.5e-4 rms << 1.5e-3.
// h stored as f16[256] in LDS, double-buffered, unit-swizzled:
// unit u (8 halves) stored at u ^ (u>>3). Per ds_read_b128 wavefront the 16
// distinct units hit every bank-quad exactly twice (2-way = free, m136).
// Reduction: reduce-scatter over lane bits {0,1,3} + butterfly over bit2
// (verbatim from rounds 5/8, correctness-proven).
// ---------------------------------------------------------------------------
__global__ void __launch_bounds__(512)
__attribute__((amdgpu_waves_per_eu(2, 2)))
qrnn_phase2(const float* __restrict__ W, const float* __restrict__ inp,
            float* __restrict__ out)
{
    const int tid = threadIdx.x;
    const int r = tid & 15;
    const int g = tid >> 4;                 // [0, 32)
    const bool b0 = (r & 1) != 0;
    const bool b1 = (r & 2) != 0;
    const bool b2 = (r & 4) != 0;
    const bool b3 = (r & 8) != 0;
    const int m_r = (r & 3) | ((r >> 1) & 4);   // this lane's output row
    const int i_out = 8 * g + m_r;

    __shared__ unsigned short hbuf[2][HID];     // f16 bits, unit-swizzled
    if (tid < HID) hbuf[0][tid] = 0;            // zeros: swizzle-invariant

    // Weight tile: wp[m][k] = f16{ W[8g+m][16r+2k], W[8g+m][16r+2k+1] }
    v2h wp[8][8];
#pragma unroll
    for (int m = 0; m < 8; ++m) {
        const float* wrow = W + (size_t)(8 * g + m) * (2 * HID) + r * 16;
#pragma unroll
        for (int k = 0; k < 8; ++k)
            wp[m][k] = (v2h){ (_Float16)wrow[2 * k], (_Float16)wrow[2 * k + 1] };
        PIN8(wp[m]);
    }

    // Swizzled read byte-offsets (loop-invariant). Lane reads units 2r, 2r+1.
    const int u1 = 2 * r, u2 = 2 * r + 1;
    const int rb1 = (u1 ^ (u1 >> 3)) * 16;
    const int rb2 = (u2 ^ (u2 >> 3)) * 16;
    // Swizzled write half-index for h_new[i_out]
    const int uo = i_out >> 3;
    const int wh = (uo ^ (uo >> 3)) * 8 + (i_out & 7);

    float ip = inp[i_out];  // inp[0][i_out]
    float h = 0.0f;
    __syncthreads();

    auto step = [&](const unsigned short* __restrict__ src,
                    unsigned short* __restrict__ dst, int tnext) {
        // 16 h halves: 2 swizzled ds_read_b128 (2-way bank alias max)
        const char* sb = (const char*)src;
        const uint4 ua = *reinterpret_cast<const uint4*>(sb + rb1);
        const uint4 ub = *reinterpret_cast<const uint4*>(sb + rb2);
        v2h hp[8];
        hp[0] = __builtin_bit_cast(v2h, ua.x);
        hp[1] = __builtin_bit_cast(v2h, ua.y);
        hp[2] = __builtin_bit_cast(v2h, ua.z);
        hp[3] = __builtin_bit_cast(v2h, ua.w);
        hp[4] = __builtin_bit_cast(v2h, ub.x);
        hp[5] = __builtin_bit_cast(v2h, ub.y);
        hp[6] = __builtin_bit_cast(v2h, ub.z);
        hp[7] = __builtin_bit_cast(v2h, ub.w);

        // Prefetch next step's inp (branchless; hidden under dot2s)
        float ip_next = inp[(tnext & (SEQ - 1)) * HID + i_out];

        // 8 partial dots, 8 dot2 each (64 instrs = 128 MACs), f32 accum
        float acc[8];
#pragma unroll
        for (int m = 0; m < 8; ++m) {
            float a = 0.0f;
#pragma unroll
            for (int k = 0; k < 8; ++k)
                a = __builtin_amdgcn_fdot2(wp[m][k], hp[k], a, false);
            acc[m] = a;
        }

        // --- DPP reduce-scatter across the 16-lane group (verified R5/R8) ---
        float q[4];
#pragma unroll
        for (int j = 0; j < 4; ++j) {
            float give = b0 ? acc[2 * j] : acc[2 * j + 1];
            float keep = b0 ? acc[2 * j + 1] : acc[2 * j];
            q[j] = keep + dpp_mov<0xB1>(give);
        }
        float s2[2];
#pragma unroll
        for (int k2 = 0; k2 < 2; ++k2) {
            float give = b1 ? q[2 * k2] : q[2 * k2 + 1];
            float keep = b1 ? q[2 * k2 + 1] : q[2 * k2];
            s2[k2] = keep + dpp_mov<0x4E>(give);
        }
        float give3 = b3 ? s2[0] : s2[1];
        float keep3 = b3 ? s2[1] : s2[0];
        float ssum = keep3 + dpp_mov<0x128>(give3);
        float a4  = dpp_mov<0x124>(ssum);   // src (i-4)&15
        float a12 = dpp_mov<0x12C>(ssum);   // src (i+4)&15
        float total = ssum + (b2 ? a4 : a12);

        float d = total + ip;
        // tanh(d) = 1 - 2/(exp(2d)+1)
        float e = __expf(2.0f * d);
        h = 1.0f - 2.0f / (e + 1.0f);

        // Writer lanes (b2==0) store f16(h) at the swizzled half position
        if (!b2) dst[wh] = __builtin_bit_cast(unsigned short, (_Float16)h);

        ip = ip_next;
        __syncthreads();
    };

#pragma unroll 1
    for (int t = 0; t < SEQ; t += 2) {
        step(&hbuf[0][0], &hbuf[1][0], t + 1);
        step(&hbuf[1][0], &hbuf[0][0], t + 2);
    }

    // h_final in f32 (pre-rounding) from the last step
    if (!b2) out[i_out] = h;
}

extern "C" void kernel_launch(void* const* d_in, const int* in_sizes, int n_in,
                              void* d_out, int out_size, void* d_ws, size_t ws_size,
                              hipStream_t stream)
{
    const int*   idx = (const int*)d_in[0];
    const float* emb = (const float*)d_in[1];
    const float* W   = (const float*)d_in[2];
    const float* b   = (const float*)d_in[3];
    float* out = (float*)d_out;
    float* inp = (float*)d_ws;  // SEQ*HID*4 = 512 KB scratch

    qrnn_phase1<<<SEQ, HID, 0, stream>>>(idx, emb, W, b, inp);
    qrnn_phase2<<<1, 512, 0, stream>>>(W, inp, out);
}